// Round 6
// baseline (336.567 us; speedup 1.0000x reference)
//
#include <hip/hip_runtime.h>

// ---------------------------------------------------------------------------
// AttentionHead: B=4, C=256, N=4096, QK=64. Column-softmax attention.
// R18 = R17 + ONE change: k_attn PV wave-tile 64i x 16c -> 32i x 32c
// (ih = wid>>3 picks i-half, cw = wid&7 picks 32-c strip).
// Theory: k_attn is LDS-pipe bound via redundant P reads -- R12/R17 had all
// 16 waves each re-read the whole 64x256 P tile (512 ds_read_b128/iter ~6.1K
// cyc + 2K conflict cyc of the 15.6K cyc/iter). 32ix32c halves P-read volume
// (each wave reads only its 32 rows); V traffic doubles (each line read by
// the 2 ih-waves) but rides the VMEM pipe, overlapping LDS. S phase, grid,
// barriers, LDS size all unchanged. Falsifiable: conflicts 8.4M -> ~4.2M.
// Other kernels byte-identical to R17 (V pitch pad kept, attT aliases xT).
// ---------------------------------------------------------------------------

typedef unsigned short u16;
typedef __attribute__((ext_vector_type(8))) unsigned short ushort8;
typedef __attribute__((ext_vector_type(8))) __bf16 bf16x8;
typedef __attribute__((ext_vector_type(4))) float f32x4;

#define MFMA16(a, b, c) __builtin_amdgcn_mfma_f32_16x16x32_bf16((a), (b), (c), 0, 0, 0)

#define VP 4352  // padded Vc row pitch in u16 (8704 B = 8192 + 512)

__device__ __forceinline__ u16 f2bf(float f) {
  unsigned int u = __builtin_bit_cast(unsigned int, f);
  u += 0x7FFFu + ((u >> 16) & 1u);  // round-to-nearest-even
  return (u16)(u >> 16);
}

__device__ __forceinline__ bf16x8 ld8(const u16* p) {
  return __builtin_bit_cast(bf16x8, *reinterpret_cast<const ushort8*>(p));
}

__device__ __forceinline__ f32x4 fz4() {
  f32x4 z = {0.f, 0.f, 0.f, 0.f};
  return z;
}

// ---- convert all weight matrices fp32 -> bf16 (one launch) ----------------
__global__ __launch_bounds__(256) void k_convert(
    const float* __restrict__ wq, const float* __restrict__ wk,
    const float* __restrict__ wv, const float* __restrict__ w1,
    const float* __restrict__ w2, u16* __restrict__ dq, u16* __restrict__ dk,
    u16* __restrict__ dv, u16* __restrict__ d1, u16* __restrict__ d2) {
  int i = blockIdx.x * 256 + threadIdx.x;
  if (i < 16384)       dq[i]           = f2bf(wq[i]);
  else if (i < 32768)  dk[i - 16384]   = f2bf(wk[i - 16384]);
  else if (i < 98304)  dv[i - 32768]   = f2bf(wv[i - 32768]);
  else if (i < 163840) d1[i - 98304]   = f2bf(w1[i - 98304]);
  else                 d2[i - 163840]  = f2bf(w2[i - 163840]);
}

// ---- x [b][256][4096] fp32 -> xT [b][4096][256] bf16 (LDS-tiled) ----------
__global__ __launch_bounds__(256) void k_transpose(const float* __restrict__ x,
                                                   u16* __restrict__ xT) {
  __shared__ float t[64][65];
  int n0 = blockIdx.x * 64, c0 = blockIdx.y * 64, b = blockIdx.z;
  int tx = threadIdx.x & 63, ty = threadIdx.x >> 6;
  const float* xb = x + ((size_t)b * 256 + c0) * 4096 + n0;
#pragma unroll
  for (int i = 0; i < 64; i += 4) t[ty + i][tx] = xb[(size_t)(ty + i) * 4096 + tx];
  __syncthreads();
  u16* xo = xT + ((size_t)b * 4096 + n0) * 256 + c0;
#pragma unroll
  for (int i = 0; i < 64; i += 4) xo[(size_t)(ty + i) * 256 + tx] = f2bf(t[tx][ty + i]);
}

// ---- fused QKV projection: 32-pos tiles, grid 512 linear (b = id&3) -------
__global__ __launch_bounds__(256) void k_proj(
    const u16* __restrict__ xT, const u16* __restrict__ wq,
    const u16* __restrict__ wk, const u16* __restrict__ wv,
    const float* __restrict__ bQ, const float* __restrict__ bK,
    const float* __restrict__ bV, const float* __restrict__ PE,
    u16* __restrict__ Qt, u16* __restrict__ Kt, u16* __restrict__ Vc) {
  int b = blockIdx.x & 3, n0 = (blockIdx.x >> 2) * 32;
  int lane = threadIdx.x & 63, wid = threadIdx.x >> 6;
  int l15 = lane & 15, g = lane >> 4;
  const u16* xrow = xT + ((size_t)b * 4096 + n0) * 256;

  f32x4 aq[2], ak[2], av[4][2];
#pragma unroll
  for (int m = 0; m < 2; ++m) { aq[m] = fz4(); ak[m] = fz4(); }
#pragma unroll
  for (int m = 0; m < 4; ++m)
#pragma unroll
    for (int n = 0; n < 2; ++n) av[m][n] = fz4();

  for (int kk = 0; kk < 8; ++kk) {
    int ko = kk * 32 + g * 8;
    bf16x8 xa[2];
#pragma unroll
    for (int m = 0; m < 2; ++m) xa[m] = ld8(xrow + (16 * m + l15) * 256 + ko);
    bf16x8 fq = ld8(wq + (16 * wid + l15) * 256 + ko);
    bf16x8 fk = ld8(wk + (16 * wid + l15) * 256 + ko);
#pragma unroll
    for (int m = 0; m < 2; ++m) {
      aq[m] = MFMA16(xa[m], fq, aq[m]);
      ak[m] = MFMA16(xa[m], fk, ak[m]);
    }
    bf16x8 fv[4];
#pragma unroll
    for (int m = 0; m < 4; ++m) fv[m] = ld8(wv + (64 * wid + 16 * m + l15) * 256 + ko);
#pragma unroll
    for (int m = 0; m < 4; ++m)
#pragma unroll
      for (int n = 0; n < 2; ++n) av[m][n] = MFMA16(fv[m], xa[n], av[m][n]);
  }

  int o = 16 * wid + l15;
#pragma unroll
  for (int m = 0; m < 2; ++m)
#pragma unroll
    for (int r = 0; r < 4; ++r) {
      int pos = n0 + 16 * m + 4 * g + r;
      float pe = PE[o * 4096 + pos];
      Qt[((size_t)b * 4096 + pos) * 64 + o] = f2bf(aq[m][r] + bQ[o] + pe);
      Kt[((size_t)b * 4096 + pos) * 64 + o] = f2bf(ak[m][r] + bK[o] + pe);
    }
#pragma unroll
  for (int m = 0; m < 4; ++m) {
    int ov = 64 * wid + 16 * m + 4 * g;
#pragma unroll
    for (int r = 0; r < 4; ++r) {
      float bvv = bV[ov + r];
#pragma unroll
      for (int n = 0; n < 2; ++n) {
        int pos = n0 + 16 * n + l15;
        Vc[((size_t)b * 256 + ov + r) * VP + pos] = f2bf(av[m][n][r] + bvv);
      }
    }
  }
}

// ---- pass 1: column sums, 512 thr, grid 256 linear (b = id&3) -------------
__global__ __launch_bounds__(512) void k_colsum(const u16* __restrict__ Qt,
                                                const u16* __restrict__ Kt,
                                                float* __restrict__ rs) {
  __shared__ float ps[8][16];
  int b = blockIdx.x & 3, j0 = (blockIdx.x >> 2) * 64;
  int lane = threadIdx.x & 63, wid = threadIdx.x >> 6;  // wid in [0,8)
  int l15 = lane & 15, g = lane >> 4;
  int w4 = wid & 3, ihalf = wid >> 2;
  const u16* qb = Qt + (size_t)b * 262144;
  const u16* kb = Kt + (size_t)b * 262144;
  int j = j0 + 16 * w4 + l15;
  bf16x8 fk[2];
#pragma unroll
  for (int h = 0; h < 2; ++h) fk[h] = ld8(kb + j * 64 + h * 32 + 8 * g);
  float part = 0.f;
  for (int i0 = ihalf * 2048; i0 < ihalf * 2048 + 2048; i0 += 64) {
    f32x4 acc[4];
#pragma unroll
    for (int m = 0; m < 4; ++m) acc[m] = fz4();
#pragma unroll
    for (int m = 0; m < 4; ++m) {
      const u16* qr = qb + (i0 + 16 * m + l15) * 64;
      acc[m] = MFMA16(ld8(qr + 8 * g), fk[0], acc[m]);
      acc[m] = MFMA16(ld8(qr + 32 + 8 * g), fk[1], acc[m]);
    }
#pragma unroll
    for (int m = 0; m < 4; ++m)
#pragma unroll
      for (int r = 0; r < 4; ++r) part += __expf(acc[m][r] * 0.125f);
  }
  part += __shfl_xor(part, 16);
  part += __shfl_xor(part, 32);
  if (g == 0) ps[wid][l15] = part;
  __syncthreads();
  if (ihalf == 0 && g == 0)
    rs[b * 4096 + j] = 1.0f / (ps[w4][l15] + ps[w4 + 4][l15]);
}

// ---- pass 2: attention, 1024 thr, grid 256 linear (b = id&3, XCD-pin) -----
// S phase = R12 verbatim. PV re-tiled: wave (ih=wid>>3, cw=wid&7) owns
// 32i x 32c -> each wave reads only its 32 P rows (half the LDS traffic);
// V strips read by 2 waves each (VMEM pipe, overlaps LDS).
__global__ __launch_bounds__(1024) void k_attn(
    const u16* __restrict__ Qt, const u16* __restrict__ Kt,
    const u16* __restrict__ Vc, const float* __restrict__ rs,
    u16* __restrict__ attT) {
  __shared__ u16 P[64][264];  // 256 j + pad (row 528 B, 33x16B)
  int b = blockIdx.x & 3, i0 = (blockIdx.x >> 2) * 64;
  int lane = threadIdx.x & 63, wid = threadIdx.x >> 6;  // wid in [0,16)
  int l15 = lane & 15, g = lane >> 4;
  int ih = wid >> 3, cw = wid & 7;  // PV tile: i-half, 32-c strip
  const u16* qb = Qt + (size_t)b * 262144;
  const u16* kb = Kt + (size_t)b * 262144;
  const u16* vb = Vc + (size_t)b * 256 * VP;
  const float* rsb = rs + b * 4096;

  bf16x8 aq[4][2];  // block's Q rows (i = i0+16m+l15), held for all j
#pragma unroll
  for (int m = 0; m < 4; ++m)
#pragma unroll
    for (int h = 0; h < 2; ++h)
      aq[m][h] = ld8(qb + (i0 + 16 * m + l15) * 64 + h * 32 + 8 * g);

  f32x4 oacc[2][2];  // [m][cs]: i = i0+32ih+16m+4g+r, c = 32cw+16cs+l15
#pragma unroll
  for (int m = 0; m < 2; ++m)
#pragma unroll
    for (int cs = 0; cs < 2; ++cs) oacc[m][cs] = fz4();

  for (int j0 = 0; j0 < 4096; j0 += 256) {
    // S + exp for this wave's 16-j strip (j = j0 + 16*wid + l15)
    const u16* kr = kb + (size_t)(j0 + 16 * wid + l15) * 64;
    bf16x8 fk0 = ld8(kr + 8 * g);
    bf16x8 fk1 = ld8(kr + 32 + 8 * g);
    float rsc = rsb[j0 + 16 * wid + l15];
    f32x4 s[4];
#pragma unroll
    for (int m = 0; m < 4; ++m) {
      s[m] = fz4();
      s[m] = MFMA16(aq[m][0], fk0, s[m]);
      s[m] = MFMA16(aq[m][1], fk1, s[m]);
    }
#pragma unroll
    for (int m = 0; m < 4; ++m)
#pragma unroll
      for (int r = 0; r < 4; ++r)
        P[16 * m + 4 * g + r][16 * wid + l15] = f2bf(__expf(s[m][r] * 0.125f) * rsc);
    __syncthreads();
    // PV: A = P rows (ih half, 2 m), B = V rows (strip 32cw, 2 cs)
#pragma unroll
    for (int h = 0; h < 8; ++h) {
      bf16x8 ap[2];
#pragma unroll
      for (int m = 0; m < 2; ++m)
        ap[m] = ld8(&P[32 * ih + 16 * m + l15][h * 32 + 8 * g]);
      bf16x8 fv[2];
#pragma unroll
      for (int cs = 0; cs < 2; ++cs)
        fv[cs] = ld8(vb + (size_t)(32 * cw + 16 * cs + l15) * VP + j0 + h * 32 + 8 * g);
#pragma unroll
      for (int m = 0; m < 2; ++m)
#pragma unroll
        for (int cs = 0; cs < 2; ++cs)
          oacc[m][cs] = MFMA16(ap[m], fv[cs], oacc[m][cs]);
    }
    __syncthreads();
  }
#pragma unroll
  for (int m = 0; m < 2; ++m)
#pragma unroll
    for (int cs = 0; cs < 2; ++cs) {
      int c = 32 * cw + 16 * cs + l15;
#pragma unroll
      for (int r = 0; r < 4; ++r) {
        int pos = i0 + 32 * ih + 16 * m + 4 * g + r;
        attT[((size_t)b * 4096 + pos) * 256 + c] = f2bf(oacc[m][cs][r]);
      }
    }
}

// ---- fused MLP, 512 thr, grid 256 linear (b = id&3) -----------------------
__global__ __launch_bounds__(512) void k_mlp(
    const u16* __restrict__ attT, const u16* __restrict__ w1,
    const float* __restrict__ b1, const u16* __restrict__ w2,
    const float* __restrict__ b2, const float* __restrict__ x,
    float* __restrict__ out) {
  __shared__ u16 hdnS[64][264];
  int b = blockIdx.x & 3, n0 = (blockIdx.x >> 2) * 64;
  int lane = threadIdx.x & 63, wid = threadIdx.x >> 6;  // wid in [0,8)
  int l15 = lane & 15, g = lane >> 4;
  const u16* arow = attT + ((size_t)b * 4096 + n0) * 256;

  // stage 1: hdn = mish(att @ W1^T + b1) -> LDS; wave strip = 32 h-channels
  {
    f32x4 acc[4][2];
#pragma unroll
    for (int m = 0; m < 4; ++m)
#pragma unroll
      for (int n = 0; n < 2; ++n) acc[m][n] = fz4();
    for (int kk = 0; kk < 8; ++kk) {
      int ko = kk * 32 + 8 * g;
      bf16x8 am[4], bn[2];
#pragma unroll
      for (int m = 0; m < 4; ++m) am[m] = ld8(arow + (16 * m + l15) * 256 + ko);
#pragma unroll
      for (int n = 0; n < 2; ++n) bn[n] = ld8(w1 + (32 * wid + 16 * n + l15) * 256 + ko);
#pragma unroll
      for (int m = 0; m < 4; ++m)
#pragma unroll
        for (int n = 0; n < 2; ++n) acc[m][n] = MFMA16(am[m], bn[n], acc[m][n]);
    }
#pragma unroll
    for (int m = 0; m < 4; ++m)
#pragma unroll
      for (int n = 0; n < 2; ++n) {
        int hh = 32 * wid + 16 * n + l15;
        float bb = b1[hh];
#pragma unroll
        for (int r = 0; r < 4; ++r) {
          float v = acc[m][n][r] + bb;
          float sp = (v > 15.f) ? v : __logf(1.f + __expf(v));
          float e2 = __expf(-2.f * sp);
          float th = (1.f - e2) / (1.f + e2);
          hdnS[16 * m + 4 * g + r][hh] = f2bf(v * th);
        }
      }
  }
  __syncthreads();

  // stage 2: out = hdn @ W2^T + b2 + x; wave strip = 32 o-channels
  {
    f32x4 acc[2][4];
#pragma unroll
    for (int m = 0; m < 2; ++m)
#pragma unroll
      for (int n = 0; n < 4; ++n) acc[m][n] = fz4();
    for (int kk = 0; kk < 8; ++kk) {
      int ko = kk * 32 + 8 * g;
      bf16x8 am[2], bn[4];
#pragma unroll
      for (int m = 0; m < 2; ++m) am[m] = ld8(w2 + (32 * wid + 16 * m + l15) * 256 + ko);
#pragma unroll
      for (int n = 0; n < 4; ++n) bn[n] = ld8(&hdnS[16 * n + l15][ko]);
#pragma unroll
      for (int m = 0; m < 2; ++m)
#pragma unroll
        for (int n = 0; n < 4; ++n) acc[m][n] = MFMA16(am[m], bn[n], acc[m][n]);
    }
#pragma unroll
    for (int m = 0; m < 2; ++m)
#pragma unroll
      for (int r = 0; r < 4; ++r) {
        int o = 32 * wid + 16 * m + 4 * g + r;
        float bias = b2[o];
#pragma unroll
        for (int n = 0; n < 4; ++n) {
          int pos = n0 + 16 * n + l15;
          size_t idx = ((size_t)b * 256 + o) * 4096 + pos;
          out[idx] = acc[m][n][r] + bias + x[idx];
        }
      }
  }
}

// ---- workspace layout (bytes) ---------------------------------------------
// attT aliases xT (xT dead after k_proj; attT written by k_attn, read k_mlp).
#define WS_XT 0u          //  8,388,608  xT  [4][4096][256] bf16  (= attT)
#define WS_ATT 0u         //  8,388,608  attT[4][4096][256] bf16  (= xT)
#define WS_QT 8388608u    //  2,097,152  Qt  [4][4096][64]  bf16
#define WS_KT 10485760u   //  2,097,152  Kt  [4][4096][64]  bf16
#define WS_VC 12582912u   //  8,912,896  Vc  [4][256][4352] bf16 (padded)
#define WS_RS 21495808u   //     65,536  rs  [4][4096]      fp32
#define WS_WQ 21561344u   //     32,768
#define WS_WK 21594112u   //     32,768
#define WS_WV 21626880u   //    131,072
#define WS_W1 21757952u   //    131,072
#define WS_W2 21889024u   //    131,072   (end: 22,020,096 < 29,884,416)

extern "C" void kernel_launch(void* const* d_in, const int* in_sizes, int n_in,
                              void* d_out, int out_size, void* d_ws, size_t ws_size,
                              hipStream_t stream) {
  (void)in_sizes; (void)n_in; (void)out_size; (void)ws_size;
  const float* x  = (const float*)d_in[0];
  const float* WQ = (const float*)d_in[1];
  const float* bQ = (const float*)d_in[2];
  const float* WK = (const float*)d_in[3];
  const float* bK = (const float*)d_in[4];
  const float* WV = (const float*)d_in[5];
  const float* bV = (const float*)d_in[6];
  const float* PE = (const float*)d_in[7];
  const float* W1 = (const float*)d_in[8];
  const float* b1 = (const float*)d_in[9];
  const float* W2 = (const float*)d_in[10];
  const float* b2 = (const float*)d_in[11];
  float* out = (float*)d_out;
  char* ws = (char*)d_ws;

  u16* xT   = (u16*)(ws + WS_XT);
  u16* Qt   = (u16*)(ws + WS_QT);
  u16* Kt   = (u16*)(ws + WS_KT);
  u16* Vc   = (u16*)(ws + WS_VC);
  u16* attT = (u16*)(ws + WS_ATT);
  float* rs = (float*)(ws + WS_RS);
  u16* wqB  = (u16*)(ws + WS_WQ);
  u16* wkB  = (u16*)(ws + WS_WK);
  u16* wvB  = (u16*)(ws + WS_WV);
  u16* w1B  = (u16*)(ws + WS_W1);
  u16* w2B  = (u16*)(ws + WS_W2);

  k_convert<<<896, 256, 0, stream>>>(WQ, WK, WV, W1, W2, wqB, wkB, wvB, w1B, w2B);
  k_transpose<<<dim3(64, 4, 4), 256, 0, stream>>>(x, xT);
  k_proj<<<512, 256, 0, stream>>>(xT, wqB, wkB, wvB, bQ, bK, bV, PE, Qt, Kt, Vc);
  k_colsum<<<256, 512, 0, stream>>>(Qt, Kt, rs);
  k_attn<<<256, 1024, 0, stream>>>(Qt, Kt, Vc, rs, attT);
  k_mlp<<<256, 512, 0, stream>>>(attT, w1B, b1, w2B, b2, x, out);
}

// Round 7
// 218.451 us; speedup vs baseline: 1.5407x; 1.5407x over previous
//
#include <hip/hip_runtime.h>

// ---------------------------------------------------------------------------
// AttentionHead: B=4, C=256, N=4096, QK=64. Column-softmax attention.
// R19: fragment-major layouts for Q/K/V. Evidence: duration tracks global
// gather count (R12/R17 8 V-gathers ~105us; R13/R16/R18 2x gathers 155-165us
// across three different structures) -> each 16-scattered-line gather costs
// ~95cyc (~6cyc/line TA serialization). Fix: store Q/K/V so one ld8 is a
// 64-lane x 16B CONTIGUOUS 1KB burst (lane = idx15 + 16*kchunk, matching
// the MFMA A/B fragment consumption order). k_proj writes swizzled; k_colsum
// and k_attn load with base + lane*8. PV tiling stays R18's 32ix32c (P-read
// halving is free now; V lines L1-shared by the ih-pair). VP pad dropped.
// attT aliases xT. Workspace end: 21,495,808 bytes.
// ---------------------------------------------------------------------------

typedef unsigned short u16;
typedef __attribute__((ext_vector_type(8))) unsigned short ushort8;
typedef __attribute__((ext_vector_type(8))) __bf16 bf16x8;
typedef __attribute__((ext_vector_type(4))) float f32x4;

#define MFMA16(a, b, c) __builtin_amdgcn_mfma_f32_16x16x32_bf16((a), (b), (c), 0, 0, 0)

__device__ __forceinline__ u16 f2bf(float f) {
  unsigned int u = __builtin_bit_cast(unsigned int, f);
  u += 0x7FFFu + ((u >> 16) & 1u);  // round-to-nearest-even
  return (u16)(u >> 16);
}

__device__ __forceinline__ bf16x8 ld8(const u16* p) {
  return __builtin_bit_cast(bf16x8, *reinterpret_cast<const ushort8*>(p));
}

__device__ __forceinline__ f32x4 fz4() {
  f32x4 z = {0.f, 0.f, 0.f, 0.f};
  return z;
}

// Fragment-major addressing (u16 units), per batch:
//  Qf/Kf: [istrip(256)][dc(2)][lane(64)][8]   -> ((istrip*2+dc)<<9) + lane*8
//  Vf   : [cstrip(16)][jchunk(128)][lane(64)][8] -> ((cstrip*128+jc)<<9)+lane*8
// lane = idx15 + 16*g holds tensor[idx = strip*16 + idx15][k = kchunk*8 + e].

// ---- convert all weight matrices fp32 -> bf16 (one launch) ----------------
__global__ __launch_bounds__(256) void k_convert(
    const float* __restrict__ wq, const float* __restrict__ wk,
    const float* __restrict__ wv, const float* __restrict__ w1,
    const float* __restrict__ w2, u16* __restrict__ dq, u16* __restrict__ dk,
    u16* __restrict__ dv, u16* __restrict__ d1, u16* __restrict__ d2) {
  int i = blockIdx.x * 256 + threadIdx.x;
  if (i < 16384)       dq[i]           = f2bf(wq[i]);
  else if (i < 32768)  dk[i - 16384]   = f2bf(wk[i - 16384]);
  else if (i < 98304)  dv[i - 32768]   = f2bf(wv[i - 32768]);
  else if (i < 163840) d1[i - 98304]   = f2bf(w1[i - 98304]);
  else                 d2[i - 163840]  = f2bf(w2[i - 163840]);
}

// ---- x [b][256][4096] fp32 -> xT [b][4096][256] bf16 (LDS-tiled) ----------
__global__ __launch_bounds__(256) void k_transpose(const float* __restrict__ x,
                                                   u16* __restrict__ xT) {
  __shared__ float t[64][65];
  int n0 = blockIdx.x * 64, c0 = blockIdx.y * 64, b = blockIdx.z;
  int tx = threadIdx.x & 63, ty = threadIdx.x >> 6;
  const float* xb = x + ((size_t)b * 256 + c0) * 4096 + n0;
#pragma unroll
  for (int i = 0; i < 64; i += 4) t[ty + i][tx] = xb[(size_t)(ty + i) * 4096 + tx];
  __syncthreads();
  u16* xo = xT + ((size_t)b * 4096 + n0) * 256 + c0;
#pragma unroll
  for (int i = 0; i < 64; i += 4) xo[(size_t)(ty + i) * 256 + tx] = f2bf(t[tx][ty + i]);
}

// ---- fused QKV projection: 32-pos tiles, grid 512 linear (b = id&3) -------
// Epilogue writes Q/K/V in fragment-major order (see map above).
__global__ __launch_bounds__(256) void k_proj(
    const u16* __restrict__ xT, const u16* __restrict__ wq,
    const u16* __restrict__ wk, const u16* __restrict__ wv,
    const float* __restrict__ bQ, const float* __restrict__ bK,
    const float* __restrict__ bV, const float* __restrict__ PE,
    u16* __restrict__ Qt, u16* __restrict__ Kt, u16* __restrict__ Vc) {
  int b = blockIdx.x & 3, n0 = (blockIdx.x >> 2) * 32;
  int lane = threadIdx.x & 63, wid = threadIdx.x >> 6;
  int l15 = lane & 15, g = lane >> 4;
  const u16* xrow = xT + ((size_t)b * 4096 + n0) * 256;

  f32x4 aq[2], ak[2], av[4][2];
#pragma unroll
  for (int m = 0; m < 2; ++m) { aq[m] = fz4(); ak[m] = fz4(); }
#pragma unroll
  for (int m = 0; m < 4; ++m)
#pragma unroll
    for (int n = 0; n < 2; ++n) av[m][n] = fz4();

  for (int kk = 0; kk < 8; ++kk) {
    int ko = kk * 32 + g * 8;
    bf16x8 xa[2];
#pragma unroll
    for (int m = 0; m < 2; ++m) xa[m] = ld8(xrow + (16 * m + l15) * 256 + ko);
    bf16x8 fq = ld8(wq + (16 * wid + l15) * 256 + ko);
    bf16x8 fk = ld8(wk + (16 * wid + l15) * 256 + ko);
#pragma unroll
    for (int m = 0; m < 2; ++m) {
      aq[m] = MFMA16(xa[m], fq, aq[m]);
      ak[m] = MFMA16(xa[m], fk, ak[m]);
    }
    bf16x8 fv[4];
#pragma unroll
    for (int m = 0; m < 4; ++m) fv[m] = ld8(wv + (64 * wid + 16 * m + l15) * 256 + ko);
#pragma unroll
    for (int m = 0; m < 4; ++m)
#pragma unroll
      for (int n = 0; n < 2; ++n) av[m][n] = MFMA16(fv[m], xa[n], av[m][n]);
  }

  // Q/K fragment writes: o = 16*wid+l15 (col), pos = n0+16m+4g+r (row)
  int o = 16 * wid + l15;
  int dc = wid >> 1;                      // o>>5
  int gp = (16 * (wid & 1) + l15) >> 3;   // (o&31)>>3
  int eo = l15 & 7;                       // o&7
  u16* qf = Qt + (size_t)b * 262144;
  u16* kf = Kt + (size_t)b * 262144;
#pragma unroll
  for (int m = 0; m < 2; ++m) {
    int istrip = (n0 >> 4) + m;
#pragma unroll
    for (int r = 0; r < 4; ++r) {
      int pos = n0 + 16 * m + 4 * g + r;
      float pe = PE[o * 4096 + pos];
      size_t a = (size_t)(((istrip * 2 + dc) << 9) + ((4 * g + r) + 16 * gp) * 8 + eo);
      qf[a] = f2bf(aq[m][r] + bQ[o] + pe);
      kf[a] = f2bf(ak[m][r] + bK[o] + pe);
    }
  }
  // V fragment writes: c = 64wid+16m+4g+r (row idx), pos = n0+16n+l15 (col k)
  u16* vf = Vc + (size_t)b * 1048576;
  int jchunk = n0 >> 5;
#pragma unroll
  for (int m = 0; m < 4; ++m) {
    int cstrip = 4 * wid + m;
#pragma unroll
    for (int r = 0; r < 4; ++r) {
      int c15 = 4 * g + r;
      float bvv = bV[64 * wid + 16 * m + c15];
#pragma unroll
      for (int n = 0; n < 2; ++n) {
        size_t a = (size_t)(((cstrip * 128 + jchunk) << 9) +
                            (c15 + 16 * (2 * n + (l15 >> 3))) * 8 + (l15 & 7));
        vf[a] = f2bf(av[m][n][r] + bvv);
      }
    }
  }
}

// ---- pass 1: column sums, 512 thr, grid 256 linear (b = id&3) -------------
// Q/K loads now coalesced fragment bursts (base + lane*8).
__global__ __launch_bounds__(512) void k_colsum(const u16* __restrict__ Qt,
                                                const u16* __restrict__ Kt,
                                                float* __restrict__ rs) {
  __shared__ float ps[8][16];
  int b = blockIdx.x & 3, j0 = (blockIdx.x >> 2) * 64;
  int lane = threadIdx.x & 63, wid = threadIdx.x >> 6;  // wid in [0,8)
  int l15 = lane & 15, g = lane >> 4;
  int w4 = wid & 3, ihalf = wid >> 2;
  const u16* qf = Qt + (size_t)b * 262144;
  const u16* kf = Kt + (size_t)b * 262144;
  int j = j0 + 16 * w4 + l15;
  int jstrip = (j0 >> 4) + w4;
  bf16x8 fk[2];
#pragma unroll
  for (int h = 0; h < 2; ++h)
    fk[h] = ld8(kf + ((jstrip * 2 + h) << 9) + lane * 8);
  float part = 0.f;
  for (int i0 = ihalf * 2048; i0 < ihalf * 2048 + 2048; i0 += 64) {
    f32x4 acc[4];
#pragma unroll
    for (int m = 0; m < 4; ++m) acc[m] = fz4();
#pragma unroll
    for (int m = 0; m < 4; ++m) {
      int ib = ((i0 >> 4) + m) * 2;
      acc[m] = MFMA16(ld8(qf + (ib << 9) + lane * 8), fk[0], acc[m]);
      acc[m] = MFMA16(ld8(qf + ((ib + 1) << 9) + lane * 8), fk[1], acc[m]);
    }
#pragma unroll
    for (int m = 0; m < 4; ++m)
#pragma unroll
      for (int r = 0; r < 4; ++r) part += __expf(acc[m][r] * 0.125f);
  }
  part += __shfl_xor(part, 16);
  part += __shfl_xor(part, 32);
  if (g == 0) ps[wid][l15] = part;
  __syncthreads();
  if (ihalf == 0 && g == 0)
    rs[b * 4096 + j] = 1.0f / (ps[w4][l15] + ps[w4 + 4][l15]);
}

// ---- pass 2: attention, 1024 thr, grid 256 linear (b = id&3, XCD-pin) -----
// All Q/K/V loads coalesced 1KB fragment bursts. PV tiling 32i x 32c
// (ih=wid>>3, cw=wid&7); V lines L1-shared by the two ih waves.
__global__ __launch_bounds__(1024) void k_attn(
    const u16* __restrict__ Qt, const u16* __restrict__ Kt,
    const u16* __restrict__ Vc, const float* __restrict__ rs,
    u16* __restrict__ attT) {
  __shared__ u16 P[64][264];  // 256 j + pad (row 528 B, 33x16B)
  int b = blockIdx.x & 3, i0 = (blockIdx.x >> 2) * 64;
  int lane = threadIdx.x & 63, wid = threadIdx.x >> 6;  // wid in [0,16)
  int l15 = lane & 15, g = lane >> 4;
  int ih = wid >> 3, cw = wid & 7;  // PV tile: i-half, 32-c strip
  const u16* qf = Qt + (size_t)b * 262144;
  const u16* kf = Kt + (size_t)b * 262144;
  const u16* vf = Vc + (size_t)b * 1048576;
  const float* rsb = rs + b * 4096;

  bf16x8 aq[4][2];  // block's Q rows (istrips i0/16 .. +3), all j
#pragma unroll
  for (int m = 0; m < 4; ++m)
#pragma unroll
    for (int h = 0; h < 2; ++h)
      aq[m][h] = ld8(qf + ((((i0 >> 4) + m) * 2 + h) << 9) + lane * 8);

  f32x4 oacc[2][2];  // [m][cs]: i = i0+32ih+16m+4g+r, c = 32cw+16cs+l15
#pragma unroll
  for (int m = 0; m < 2; ++m)
#pragma unroll
    for (int cs = 0; cs < 2; ++cs) oacc[m][cs] = fz4();

  for (int j0 = 0; j0 < 4096; j0 += 256) {
    // S + exp for this wave's 16-j strip (j = j0 + 16*wid + l15)
    int jstrip = (j0 >> 4) + wid;
    bf16x8 fk0 = ld8(kf + ((jstrip * 2 + 0) << 9) + lane * 8);
    bf16x8 fk1 = ld8(kf + ((jstrip * 2 + 1) << 9) + lane * 8);
    float rsc = rsb[j0 + 16 * wid + l15];
    f32x4 s[4];
#pragma unroll
    for (int m = 0; m < 4; ++m) {
      s[m] = fz4();
      s[m] = MFMA16(aq[m][0], fk0, s[m]);
      s[m] = MFMA16(aq[m][1], fk1, s[m]);
    }
#pragma unroll
    for (int m = 0; m < 4; ++m)
#pragma unroll
      for (int r = 0; r < 4; ++r)
        P[16 * m + 4 * g + r][16 * wid + l15] = f2bf(__expf(s[m][r] * 0.125f) * rsc);
    __syncthreads();
    // PV: A = P rows (ih half, 2 m), B = V fragment bursts (strips 2cw, 2cw+1)
#pragma unroll
    for (int h = 0; h < 8; ++h) {
      bf16x8 ap[2];
#pragma unroll
      for (int m = 0; m < 2; ++m)
        ap[m] = ld8(&P[32 * ih + 16 * m + l15][h * 32 + 8 * g]);
      bf16x8 fv[2];
#pragma unroll
      for (int cs = 0; cs < 2; ++cs)
        fv[cs] = ld8(vf + (((2 * cw + cs) * 128 + (j0 >> 5) + h) << 9) + lane * 8);
#pragma unroll
      for (int m = 0; m < 2; ++m)
#pragma unroll
        for (int cs = 0; cs < 2; ++cs)
          oacc[m][cs] = MFMA16(ap[m], fv[cs], oacc[m][cs]);
    }
    __syncthreads();
  }
#pragma unroll
  for (int m = 0; m < 2; ++m)
#pragma unroll
    for (int cs = 0; cs < 2; ++cs) {
      int c = 32 * cw + 16 * cs + l15;
#pragma unroll
      for (int r = 0; r < 4; ++r) {
        int pos = i0 + 32 * ih + 16 * m + 4 * g + r;
        attT[((size_t)b * 4096 + pos) * 256 + c] = f2bf(oacc[m][cs][r]);
      }
    }
}

// ---- fused MLP, 512 thr, grid 256 linear (b = id&3) -----------------------
__global__ __launch_bounds__(512) void k_mlp(
    const u16* __restrict__ attT, const u16* __restrict__ w1,
    const float* __restrict__ b1, const u16* __restrict__ w2,
    const float* __restrict__ b2, const float* __restrict__ x,
    float* __restrict__ out) {
  __shared__ u16 hdnS[64][264];
  int b = blockIdx.x & 3, n0 = (blockIdx.x >> 2) * 64;
  int lane = threadIdx.x & 63, wid = threadIdx.x >> 6;  // wid in [0,8)
  int l15 = lane & 15, g = lane >> 4;
  const u16* arow = attT + ((size_t)b * 4096 + n0) * 256;

  // stage 1: hdn = mish(att @ W1^T + b1) -> LDS; wave strip = 32 h-channels
  {
    f32x4 acc[4][2];
#pragma unroll
    for (int m = 0; m < 4; ++m)
#pragma unroll
      for (int n = 0; n < 2; ++n) acc[m][n] = fz4();
    for (int kk = 0; kk < 8; ++kk) {
      int ko = kk * 32 + 8 * g;
      bf16x8 am[4], bn[2];
#pragma unroll
      for (int m = 0; m < 4; ++m) am[m] = ld8(arow + (16 * m + l15) * 256 + ko);
#pragma unroll
      for (int n = 0; n < 2; ++n) bn[n] = ld8(w1 + (32 * wid + 16 * n + l15) * 256 + ko);
#pragma unroll
      for (int m = 0; m < 4; ++m)
#pragma unroll
        for (int n = 0; n < 2; ++n) acc[m][n] = MFMA16(am[m], bn[n], acc[m][n]);
    }
#pragma unroll
    for (int m = 0; m < 4; ++m)
#pragma unroll
      for (int n = 0; n < 2; ++n) {
        int hh = 32 * wid + 16 * n + l15;
        float bb = b1[hh];
#pragma unroll
        for (int r = 0; r < 4; ++r) {
          float v = acc[m][n][r] + bb;
          float sp = (v > 15.f) ? v : __logf(1.f + __expf(v));
          float e2 = __expf(-2.f * sp);
          float th = (1.f - e2) / (1.f + e2);
          hdnS[16 * m + 4 * g + r][hh] = f2bf(v * th);
        }
      }
  }
  __syncthreads();

  // stage 2: out = hdn @ W2^T + b2 + x; wave strip = 32 o-channels
  {
    f32x4 acc[2][4];
#pragma unroll
    for (int m = 0; m < 2; ++m)
#pragma unroll
      for (int n = 0; n < 4; ++n) acc[m][n] = fz4();
    for (int kk = 0; kk < 8; ++kk) {
      int ko = kk * 32 + 8 * g;
      bf16x8 am[2], bn[4];
#pragma unroll
      for (int m = 0; m < 2; ++m) am[m] = ld8(w2 + (32 * wid + 16 * m + l15) * 256 + ko);
#pragma unroll
      for (int n = 0; n < 4; ++n) bn[n] = ld8(&hdnS[16 * n + l15][ko]);
#pragma unroll
      for (int m = 0; m < 2; ++m)
#pragma unroll
        for (int n = 0; n < 4; ++n) acc[m][n] = MFMA16(am[m], bn[n], acc[m][n]);
    }
#pragma unroll
    for (int m = 0; m < 2; ++m)
#pragma unroll
      for (int r = 0; r < 4; ++r) {
        int o = 32 * wid + 16 * m + 4 * g + r;
        float bias = b2[o];
#pragma unroll
        for (int n = 0; n < 4; ++n) {
          int pos = n0 + 16 * n + l15;
          size_t idx = ((size_t)b * 256 + o) * 4096 + pos;
          out[idx] = acc[m][n][r] + bias + x[idx];
        }
      }
  }
}

// ---- workspace layout (bytes) ---------------------------------------------
// attT aliases xT (xT dead after k_proj; attT written by k_attn, read k_mlp).
#define WS_XT 0u          //  8,388,608  xT  [4][4096][256] bf16  (= attT)
#define WS_ATT 0u         //  8,388,608  attT[4][4096][256] bf16  (= xT)
#define WS_QT 8388608u    //  2,097,152  Qf  [4][256][2][64][8] bf16 (frag)
#define WS_KT 10485760u   //  2,097,152  Kf  [4][256][2][64][8] bf16 (frag)
#define WS_VC 12582912u   //  8,388,608  Vf  [4][16][128][64][8] bf16 (frag)
#define WS_RS 20971520u   //     65,536  rs  [4][4096]      fp32
#define WS_WQ 21037056u   //     32,768
#define WS_WK 21069824u   //     32,768
#define WS_WV 21102592u   //    131,072
#define WS_W1 21233664u   //    131,072
#define WS_W2 21364736u   //    131,072   (end: 21,495,808 < 29,884,416)

extern "C" void kernel_launch(void* const* d_in, const int* in_sizes, int n_in,
                              void* d_out, int out_size, void* d_ws, size_t ws_size,
                              hipStream_t stream) {
  (void)in_sizes; (void)n_in; (void)out_size; (void)ws_size;
  const float* x  = (const float*)d_in[0];
  const float* WQ = (const float*)d_in[1];
  const float* bQ = (const float*)d_in[2];
  const float* WK = (const float*)d_in[3];
  const float* bK = (const float*)d_in[4];
  const float* WV = (const float*)d_in[5];
  const float* bV = (const float*)d_in[6];
  const float* PE = (const float*)d_in[7];
  const float* W1 = (const float*)d_in[8];
  const float* b1 = (const float*)d_in[9];
  const float* W2 = (const float*)d_in[10];
  const float* b2 = (const float*)d_in[11];
  float* out = (float*)d_out;
  char* ws = (char*)d_ws;

  u16* xT   = (u16*)(ws + WS_XT);
  u16* Qt   = (u16*)(ws + WS_QT);
  u16* Kt   = (u16*)(ws + WS_KT);
  u16* Vc   = (u16*)(ws + WS_VC);
  u16* attT = (u16*)(ws + WS_ATT);
  float* rs = (float*)(ws + WS_RS);
  u16* wqB  = (u16*)(ws + WS_WQ);
  u16* wkB  = (u16*)(ws + WS_WK);
  u16* wvB  = (u16*)(ws + WS_WV);
  u16* w1B  = (u16*)(ws + WS_W1);
  u16* w2B  = (u16*)(ws + WS_W2);

  k_convert<<<896, 256, 0, stream>>>(WQ, WK, WV, W1, W2, wqB, wkB, wvB, w1B, w2B);
  k_transpose<<<dim3(64, 4, 4), 256, 0, stream>>>(x, xT);
  k_proj<<<512, 256, 0, stream>>>(xT, wqB, wkB, wvB, bQ, bK, bV, PE, Qt, Kt, Vc);
  k_colsum<<<256, 512, 0, stream>>>(Qt, Kt, rs);
  k_attn<<<256, 1024, 0, stream>>>(Qt, Kt, Vc, rs, attT);
  k_mlp<<<256, 512, 0, stream>>>(attT, w1B, b1, w2B, b2, x, out);
}